// Round 2
// baseline (192.171 us; speedup 1.0000x reference)
//
#include <hip/hip_runtime.h>
#include <math.h>

#define NCAM 6
#define CCH  64
#define DB   66
#define FH   32
#define FW   88
#define NX   128
#define NY   128
#define NZ   8
#define NPTS (NX*NY*NZ)
#define NPIX (NCAM*FH*FW)

// channel split for splat kernel
#define NSPLIT 4
#define CPT (CCH/NSPLIT)   // 16 channels per thread

// ---------------------------------------------------------------------------
// Kernel 1: per-pixel depth-net (130x64 matvec) + softmax over 66 depth bins.
// Writes feat_t [n][h][w][64] and depth_t [n][h][w][66] (softmax-normalized).
// ---------------------------------------------------------------------------
__global__ __launch_bounds__(192) void depthnet_kernel(
    const float* __restrict__ x_fov, const float* __restrict__ w_dn,
    const float* __restrict__ b_dn, float* __restrict__ feat_t,
    float* __restrict__ depth_t)
{
    const int pix = blockIdx.x;            // 0..NPIX-1
    const int w = pix % FW;
    const int h = (pix / FW) % FH;
    const int n = pix / (FW * FH);
    const int tid = threadIdx.x;

    __shared__ float xs[CCH];
    __shared__ float ys[DB + CCH];
    __shared__ float red[2];

    if (tid < CCH)
        xs[tid] = x_fov[((n * CCH + tid) * FH + h) * FW + w];
    __syncthreads();

    if (tid < DB + CCH) {
        const float4* wr4 = (const float4*)(w_dn + tid * CCH);
        float acc = b_dn[tid];
        #pragma unroll
        for (int k = 0; k < CCH / 4; ++k) {
            float4 wv = wr4[k];
            acc += wv.x * xs[4*k+0];
            acc += wv.y * xs[4*k+1];
            acc += wv.z * xs[4*k+2];
            acc += wv.w * xs[4*k+3];
        }
        ys[tid] = acc;
    }
    __syncthreads();

    // max over ys[0..65] via wave-0 butterfly
    if (tid < 64) {
        float v = ys[tid];
        if (tid < DB - 64) v = fmaxf(v, ys[64 + tid]);
        #pragma unroll
        for (int off = 32; off > 0; off >>= 1) v = fmaxf(v, __shfl_xor(v, off));
        if (tid == 0) red[0] = v;
    }
    __syncthreads();
    const float m = red[0];
    if (tid < DB) ys[tid] = expf(ys[tid] - m);
    __syncthreads();
    if (tid < 64) {
        float v = ys[tid];
        if (tid < DB - 64) v += ys[64 + tid];
        #pragma unroll
        for (int off = 32; off > 0; off >>= 1) v += __shfl_xor(v, off);
        if (tid == 0) red[1] = 1.0f / v;
    }
    __syncthreads();
    const float inv = red[1];
    if (tid < DB)                depth_t[pix * DB + tid] = ys[tid] * inv;
    else if (tid < DB + CCH)     feat_t[pix * CCH + (tid - DB)] = ys[tid];
}

// ---------------------------------------------------------------------------
// Kernel 2: project every voxel center into each camera, trilinear-sample
// vol[c,d,h,w] = depth[d,h,w]*feat[c,h,w] (factored: 4 bilinear corners,
// each 2 depth scalars + CPT contiguous feat channels), average over valid
// cameras, write coalesced to out[c][ix][iy][iz].
// Corners are PREDICATED (weight=0 when OOB) rather than branched, so all
// 8 depth loads + 16 feat float4 loads per camera issue as one batch (MLP).
// ---------------------------------------------------------------------------
__global__ __launch_bounds__(256) void splat_kernel(
    const float* __restrict__ feat_t, const float* __restrict__ depth_t,
    const float* __restrict__ points, const float* __restrict__ proj,
    float* __restrict__ out)
{
    const int gtid = blockIdx.x * 256 + threadIdx.x;
    const int wv   = gtid >> 6;           // wave id 0..2047
    const int lane = gtid & 63;
    const int ix   = wv & (NX - 1);
    const int iyb  = wv >> 7;             // 0..15
    const int iy   = iyb * 8 + (lane >> 3);
    const int iz   = lane & 7;
    const int p    = (iz * NY + iy) * NX + ix;
    const int chbase = blockIdx.y * CPT;

    const float px = points[p * 3 + 0];
    const float py = points[p * 3 + 1];
    const float pz = points[p * 3 + 2];

    float acc[CPT];
    #pragma unroll
    for (int c = 0; c < CPT; ++c) acc[c] = 0.f;
    float cnt = 0.f;

    for (int n = 0; n < NCAM; ++n) {
        const float* M = proj + n * 16;
        const float u4 = M[0] * px + M[1] * py + M[2] * pz + M[3];
        const float v4 = M[4] * px + M[5] * py + M[6] * pz + M[7];
        const float z  = M[8] * px + M[9] * py + M[10] * pz + M[11];
        const float zs = fabsf(z) > 0.001f ? z : 0.001f;
        const float u = u4 / zs;
        const float v = v4 / zs;
        const bool valid = (u >= 0.f) && (u < 1408.f) && (v >= 0.f) &&
                           (v < 512.f) && (z > 0.f) && (z < 50.f);
        if (!valid) continue;
        cnt += 1.f;
        const float gx = u * (float(FW) / 1408.f) - 0.5f;
        const float gy = v * (float(FH) / 512.f) - 0.5f;
        const float gz = z * (float(DB) / 50.f) - 0.5f;
        const float xf = floorf(gx), yf = floorf(gy), zf = floorf(gz);
        const float tx = gx - xf, ty = gy - yf, tz = gz - zf;
        const int x0 = (int)xf, y0 = (int)yf, z0 = (int)zf;

        const float wz0 = (z0 >= 0 && z0 < DB) ? (1.f - tz) : 0.f;
        const float wz1 = (z0 + 1 < DB) ? tz : 0.f;   // z0+1 >= 1 > 0 always when used
        const int zi0 = min(max(z0, 0), DB - 1);
        const int zi1 = min(max(z0 + 1, 0), DB - 1);

        // --- predicated corner setup: weights zeroed when OOB, indices clamped
        float wcorn[4];
        int   pixc[4];
        #pragma unroll
        for (int dy = 0; dy < 2; ++dy) {
            const int yi = y0 + dy;
            const bool yin = (yi >= 0) & (yi < FH);
            const int yic = min(max(yi, 0), FH - 1);
            const float wy = (dy ? ty : 1.f - ty) * (yin ? 1.f : 0.f);
            #pragma unroll
            for (int dx = 0; dx < 2; ++dx) {
                const int xi = x0 + dx;
                const bool xin = (xi >= 0) & (xi < FW);
                const int xic = min(max(xi, 0), FW - 1);
                const float wx = (dx ? tx : 1.f - tx) * (xin ? 1.f : 0.f);
                wcorn[2*dy + dx] = wx * wy;
                pixc[2*dy + dx]  = (n * FH + yic) * FW + xic;
            }
        }

        // --- batch the 8 depth taps (all independent -> overlapped in flight)
        float s[4];
        #pragma unroll
        for (int k = 0; k < 4; ++k) {
            const float* dptr = depth_t + (size_t)pixc[k] * DB;
            s[k] = wz0 * dptr[zi0] + wz1 * dptr[zi1];
        }

        // --- batch the 16 feat float4 loads, accumulate
        #pragma unroll
        for (int k = 0; k < 4; ++k) {
            const float wc = wcorn[k] * s[k];
            const float4* fptr = (const float4*)(feat_t + (size_t)pixc[k] * CCH + chbase);
            #pragma unroll
            for (int q = 0; q < CPT / 4; ++q) {
                const float4 f = fptr[q];
                acc[4*q+0] += wc * f.x;
                acc[4*q+1] += wc * f.y;
                acc[4*q+2] += wc * f.z;
                acc[4*q+3] += wc * f.w;
            }
        }
    }

    const float invc = cnt > 0.f ? 1.f / cnt : 0.f;
    const int obase = ix * (NY * NZ) + iy * NZ + iz;
    #pragma unroll
    for (int c = 0; c < CPT; ++c)
        out[(chbase + c) * NPTS + obase] = acc[c] * invc;
}

extern "C" void kernel_launch(void* const* d_in, const int* in_sizes, int n_in,
                              void* d_out, int out_size, void* d_ws, size_t ws_size,
                              hipStream_t stream) {
    const float* x_fov  = (const float*)d_in[0];   // (1,6,64,32,88)
    const float* w_dn   = (const float*)d_in[1];   // (130,64)
    const float* b_dn   = (const float*)d_in[2];   // (130,)
    const float* points = (const float*)d_in[3];   // (131072,3)
    const float* proj   = (const float*)d_in[4];   // (1,6,4,4)
    float* out = (float*)d_out;                    // (1,64,128,128,8)

    float* feat_t  = (float*)d_ws;                            // NPIX*64 floats
    float* depth_t = feat_t + (size_t)NPIX * CCH;             // NPIX*66 floats

    depthnet_kernel<<<NPIX, 192, 0, stream>>>(x_fov, w_dn, b_dn, feat_t, depth_t);

    dim3 grid(NPTS / 256, NSPLIT);
    splat_kernel<<<grid, 256, 0, stream>>>(feat_t, depth_t, points, proj, out);
}

// Round 3
// 134.204 us; speedup vs baseline: 1.4319x; 1.4319x over previous
//
#include <hip/hip_runtime.h>
#include <math.h>

#define NCAM 6
#define CCH  64
#define DB   66
#define FH   32
#define FW   88
#define NX   128
#define NY   128
#define NZ   8
#define NPTS (NX*NY*NZ)
#define NPIX (NCAM*FH*FW)
#define PPC  (FH*FW)          // pixels per camera = 2816

// ---- depthnet v2 tiling ----
#define TPX   64              // pixels per block (2816 % 64 == 0)
#define DN_T  256             // threads per block
#define WS    140             // wT row stride (floats), mult of 4 for b128
#define YSS   65              // ys row stride (odd -> conflict-free columns)
#define OFF_XS 0              // xs[64][64]            = 4096
#define OFF_WT 4096           // wT[64][140]           = 8960  (end 13056)
#define OFF_YS 4096           // ys[130][65] aliases wT = 8450 (end 12546)
#define OFF_BS 13056          // bias[130]             (end 13186)
#define OFF_IV 13186          // inv_sum[64]           (end 13250)
#define LDS_F  13250

// channel split for splat kernel
#define NSPLIT 4
#define CPT (CCH/NSPLIT)   // 16 channels per thread

// ---------------------------------------------------------------------------
// Kernel 1 v2: tiled depth-net. Each block: 64 contiguous pixels of one
// camera. Stage x[64c][64px] + w^T[64c][130] in LDS, 8px x 4out register
// tiles, then in-block softmax over 66 bins. Writes feat_t [pix][64] and
// depth_t [pix][66].
// ---------------------------------------------------------------------------
__global__ __launch_bounds__(DN_T) void depthnet_kernel(
    const float* __restrict__ x_fov, const float* __restrict__ w_dn,
    const float* __restrict__ b_dn, float* __restrict__ feat_t,
    float* __restrict__ depth_t)
{
    __shared__ float lds[LDS_F];
    float* xs   = lds + OFF_XS;
    float* wT   = lds + OFF_WT;
    float* ys   = lds + OFF_YS;   // aliases wT (dead after compute)
    float* bs   = lds + OFF_BS;
    float* invs = lds + OFF_IV;

    const int t   = threadIdx.x;
    const int T   = blockIdx.x * TPX;       // global pixel base
    const int cam = T / PPC;
    const int ph0 = T - cam * PPC;          // pixel offset within camera

    // ---- Phase A: stage bias, w^T, x tile --------------------------------
    for (int i = t; i < DB + CCH; i += DN_T) bs[i] = b_dn[i];
    for (int i = t; i < (DB + CCH) * CCH; i += DN_T) {
        const int o = i >> 6, c = i & 63;
        wT[c * WS + o] = w_dn[i];
    }
    {
        const float* xb = x_fov + (size_t)cam * CCH * PPC + ph0;
        const int q = t & 15;               // 16 quads x 4 px = 64 px
        #pragma unroll
        for (int cc = 0; cc < 4; ++cc) {
            const int c = cc * 16 + (t >> 4);
            const float4 v = *(const float4*)(xb + c * PPC + q * 4);
            *(float4*)(xs + c * 64 + q * 4) = v;
        }
    }
    __syncthreads();

    // ---- Phase B: compute y = w x + b, 8px x 4out per thread -------------
    const int pq = t & 7;                   // pixel octet: px = pq*8 + pp
    const int oq = t >> 3;                  // output quad 0..31 (outputs 4oq..)
    float acc[4][8];
    float acc2[2][8];                       // tail: outputs 128,129 (oq==0)
    #pragma unroll
    for (int a = 0; a < 4; ++a)
        #pragma unroll
        for (int p = 0; p < 8; ++p) acc[a][p] = 0.f;
    #pragma unroll
    for (int a = 0; a < 2; ++a)
        #pragma unroll
        for (int p = 0; p < 8; ++p) acc2[a][p] = 0.f;

    {
        const float* xr = xs + pq * 8;
        const float* wr = wT + oq * 4;
        const float* wr2 = wT + 128;
        for (int c = 0; c < 64; ++c) {
            const float4 xa = *(const float4*)(xr + c * 64);
            const float4 xb2 = *(const float4*)(xr + c * 64 + 4);
            const float4 wv = *(const float4*)(wr + c * WS);
            const float xv[8] = {xa.x, xa.y, xa.z, xa.w, xb2.x, xb2.y, xb2.z, xb2.w};
            const float wq[4] = {wv.x, wv.y, wv.z, wv.w};
            #pragma unroll
            for (int a = 0; a < 4; ++a)
                #pragma unroll
                for (int p = 0; p < 8; ++p) acc[a][p] += wq[a] * xv[p];
            if (oq == 0) {
                const float2 w2 = *(const float2*)(wr2 + c * WS);
                #pragma unroll
                for (int p = 0; p < 8; ++p) {
                    acc2[0][p] += w2.x * xv[p];
                    acc2[1][p] += w2.y * xv[p];
                }
            }
        }
    }
    __syncthreads();   // all wT/xs reads done; ys may now overwrite

    // ---- Phase C: y -> LDS ys[o][px] (+bias) -----------------------------
    #pragma unroll
    for (int a = 0; a < 4; ++a) {
        const int o = oq * 4 + a;
        const float b = bs[o];
        #pragma unroll
        for (int p = 0; p < 8; ++p) ys[o * YSS + pq * 8 + p] = acc[a][p] + b;
    }
    if (oq == 0) {
        #pragma unroll
        for (int a = 0; a < 2; ++a) {
            const int o = 128 + a;
            const float b = bs[o];
            #pragma unroll
            for (int p = 0; p < 8; ++p) ys[o * YSS + pq * 8 + p] = acc2[a][p] + b;
        }
    }
    __syncthreads();

    // ---- Phase D: softmax stats per pixel (wave 0, one lane per px) ------
    if (t < TPX) {
        float m = -1e30f;
        for (int o = 0; o < DB; ++o) m = fmaxf(m, ys[o * YSS + t]);
        float s = 0.f;
        for (int o = 0; o < DB; ++o) {
            const float e = expf(ys[o * YSS + t] - m);
            s += e;
            ys[o * YSS + t] = e;
        }
        invs[t] = 1.f / s;
    }
    __syncthreads();

    // ---- Phase E: coalesced stores ---------------------------------------
    for (int i = t; i < TPX * DB; i += DN_T) {
        const int px = i / DB, o = i - px * DB;
        depth_t[(size_t)T * DB + i] = ys[o * YSS + px] * invs[px];
    }
    for (int i = t; i < TPX * CCH; i += DN_T) {
        const int px = i >> 6, o = i & 63;
        feat_t[(size_t)T * CCH + i] = ys[(DB + o) * YSS + px];
    }
}

// ---------------------------------------------------------------------------
// Kernel 2: project every voxel center into each camera, trilinear-sample
// vol[c,d,h,w] = depth[d,h,w]*feat[c,h,w] (factored: 4 bilinear corners,
// each 2 depth scalars + CPT contiguous feat channels), average over valid
// cameras, write coalesced to out[c][ix][iy][iz]. Voxel coords computed
// from indices in double (bit-exact with numpy grid), no points[] gather.
// ---------------------------------------------------------------------------
__global__ __launch_bounds__(256) void splat_kernel(
    const float* __restrict__ feat_t, const float* __restrict__ depth_t,
    const float* __restrict__ proj, float* __restrict__ out)
{
    const int gtid = blockIdx.x * 256 + threadIdx.x;
    const int wv   = gtid >> 6;           // wave id 0..2047
    const int lane = gtid & 63;
    const int ix   = wv & (NX - 1);
    const int iyb  = wv >> 7;             // 0..15
    const int iy   = iyb * 8 + (lane >> 3);
    const int iz   = lane & 7;
    const int chbase = blockIdx.y * CPT;

    // bit-exact replication of numpy voxel-center grid (double -> float)
    const double DXY = 102.4 / 128.0;
    const float px = (float)(-51.2 + (ix + 0.5) * DXY);
    const float py = (float)(-51.2 + (iy + 0.5) * DXY);
    const float pz = (float)(-5.0 + (iz + 0.5) * 1.0);

    float acc[CPT];
    #pragma unroll
    for (int c = 0; c < CPT; ++c) acc[c] = 0.f;
    float cnt = 0.f;

    for (int n = 0; n < NCAM; ++n) {
        const float* M = proj + n * 16;
        const float u4 = M[0] * px + M[1] * py + M[2] * pz + M[3];
        const float v4 = M[4] * px + M[5] * py + M[6] * pz + M[7];
        const float z  = M[8] * px + M[9] * py + M[10] * pz + M[11];
        const float zs = fabsf(z) > 0.001f ? z : 0.001f;
        const float u = u4 / zs;
        const float v = v4 / zs;
        const bool valid = (u >= 0.f) && (u < 1408.f) && (v >= 0.f) &&
                           (v < 512.f) && (z > 0.f) && (z < 50.f);
        if (!valid) continue;
        cnt += 1.f;
        const float gx = u / 1408.0f * (float)FW - 0.5f;
        const float gy = v / 512.0f * (float)FH - 0.5f;
        const float gz = z / 50.0f * (float)DB - 0.5f;
        const float xf = floorf(gx), yf = floorf(gy), zf = floorf(gz);
        const float tx = gx - xf, ty = gy - yf, tz = gz - zf;
        const int x0 = (int)xf, y0 = (int)yf, z0 = (int)zf;

        const float wz0 = (z0 >= 0 && z0 < DB) ? (1.f - tz) : 0.f;
        const float wz1 = (z0 + 1 < DB) ? tz : 0.f;
        const int zi0 = min(max(z0, 0), DB - 1);
        const int zi1 = min(max(z0 + 1, 0), DB - 1);

        // predicated corner setup: weights zeroed when OOB, indices clamped
        float wcorn[4];
        int   pixc[4];
        #pragma unroll
        for (int dy = 0; dy < 2; ++dy) {
            const int yi = y0 + dy;
            const bool yin = (yi >= 0) & (yi < FH);
            const int yic = min(max(yi, 0), FH - 1);
            const float wy = (dy ? ty : 1.f - ty) * (yin ? 1.f : 0.f);
            #pragma unroll
            for (int dx = 0; dx < 2; ++dx) {
                const int xi = x0 + dx;
                const bool xin = (xi >= 0) & (xi < FW);
                const int xic = min(max(xi, 0), FW - 1);
                const float wx = (dx ? tx : 1.f - tx) * (xin ? 1.f : 0.f);
                wcorn[2*dy + dx] = wx * wy;
                pixc[2*dy + dx]  = (n * FH + yic) * FW + xic;
            }
        }

        // batch the 8 depth taps (independent -> overlapped in flight)
        float s[4];
        #pragma unroll
        for (int k = 0; k < 4; ++k) {
            const float* dptr = depth_t + (size_t)pixc[k] * DB;
            s[k] = wz0 * dptr[zi0] + wz1 * dptr[zi1];
        }

        // batch the 16 feat float4 loads, accumulate
        #pragma unroll
        for (int k = 0; k < 4; ++k) {
            const float wc = wcorn[k] * s[k];
            const float4* fptr = (const float4*)(feat_t + (size_t)pixc[k] * CCH + chbase);
            #pragma unroll
            for (int q = 0; q < CPT / 4; ++q) {
                const float4 f = fptr[q];
                acc[4*q+0] += wc * f.x;
                acc[4*q+1] += wc * f.y;
                acc[4*q+2] += wc * f.z;
                acc[4*q+3] += wc * f.w;
            }
        }
    }

    const float invc = cnt > 0.f ? 1.f / cnt : 0.f;
    const int obase = ix * (NY * NZ) + iy * NZ + iz;
    #pragma unroll
    for (int c = 0; c < CPT; ++c)
        out[(chbase + c) * NPTS + obase] = acc[c] * invc;
}

extern "C" void kernel_launch(void* const* d_in, const int* in_sizes, int n_in,
                              void* d_out, int out_size, void* d_ws, size_t ws_size,
                              hipStream_t stream) {
    const float* x_fov  = (const float*)d_in[0];   // (1,6,64,32,88)
    const float* w_dn   = (const float*)d_in[1];   // (130,64)
    const float* b_dn   = (const float*)d_in[2];   // (130,)
    const float* proj   = (const float*)d_in[4];   // (1,6,4,4)
    float* out = (float*)d_out;                    // (1,64,128,128,8)

    float* feat_t  = (float*)d_ws;                            // NPIX*64 floats
    float* depth_t = feat_t + (size_t)NPIX * CCH;             // NPIX*66 floats

    depthnet_kernel<<<NPIX / TPX, DN_T, 0, stream>>>(x_fov, w_dn, b_dn, feat_t, depth_t);

    dim3 grid(NPTS / 256, NSPLIT);
    splat_kernel<<<grid, 256, 0, stream>>>(feat_t, depth_t, proj, out);
}

// Round 6
// 101.386 us; speedup vs baseline: 1.8954x; 1.3237x over previous
//
#include <hip/hip_runtime.h>
#include <math.h>

#define NCAM 6
#define CCH  64
#define DB   66
#define FH   32
#define FW   88
#define NX   128
#define NY   128
#define NZ   8
#define NPTS (NX*NY*NZ)
#define NPIX (NCAM*FH*FW)
#define PPC  (FH*FW)          // pixels per camera = 2816

// ---- depthnet tiling ----
#define TPX   32              // pixels per block (2816 % 32 == 0) -> 528 blocks
#define DN_T  256
#define WS2   132             // wT row stride
#define YSS   35              // ys row stride (conflict-tuned)
#define OFF_XS 0              // xs[64][32]   = 2048
#define OFF_WT 2048           // wT[64][132]  = 8448 (end 10496)
#define OFF_YS 2048           // ys[130][35]  = 4550 alias wT (end 6598)
#define OFF_BS 10496          // bias[130]    (end 10626)
#define LDS_F  10626

// ---------------------------------------------------------------------------
// Kernel 1: tiled depth-net. Block = 32 contiguous pixels of one camera.
// Stage x[64c][32px] + w^T[64c][130] in LDS; 8px x 2out register tiles;
// softmax with 8 lanes/pixel + shfl_xor reduction; exp values in registers
// with STATIC indexing (fixed 9-iter unroll -> no scratch).
// ---------------------------------------------------------------------------
__global__ __launch_bounds__(DN_T) void depthnet_kernel(
    const float* __restrict__ x_fov, const float* __restrict__ w_dn,
    const float* __restrict__ b_dn, float* __restrict__ feat_t,
    float* __restrict__ depth_t)
{
    __shared__ float lds[LDS_F];
    float* xs = lds + OFF_XS;
    float* wT = lds + OFF_WT;
    float* ys = lds + OFF_YS;   // aliases wT (dead after phase B)
    float* bs = lds + OFF_BS;

    const int t   = threadIdx.x;
    const int T   = blockIdx.x * TPX;       // global pixel base
    const int cam = T / PPC;
    const int ph0 = T - cam * PPC;

    // ---- Phase A: stage bias, w^T, x tile --------------------------------
    if (t < DB + CCH) bs[t] = b_dn[t];
    for (int i = t; i < (DB + CCH) * CCH; i += DN_T) {
        const int o = i >> 6, c = i & 63;
        wT[c * WS2 + o] = w_dn[i];
    }
    {
        const float* xb = x_fov + (size_t)cam * CCH * PPC + ph0;
        const int c = t >> 2;               // 0..63
        const int q = t & 3;                // 4 quads x 4 px = 16 px per half
        #pragma unroll
        for (int h = 0; h < 2; ++h) {
            const float4 v = *(const float4*)(xb + c * PPC + h * 16 + q * 4);
            *(float4*)(xs + c * TPX + h * 16 + q * 4) = v;
        }
    }
    __syncthreads();

    // ---- Phase B: y = w x, 8px x 2out per thread -------------------------
    const int pq = t & 3;                   // pixel octet
    const int oq = t >> 2;                  // 0..63 -> outputs {2oq, 2oq+1}
    float acc[2][8];
    float acc2[2][8];                       // oq==0: outputs 128,129
    #pragma unroll
    for (int a = 0; a < 2; ++a)
        #pragma unroll
        for (int p = 0; p < 8; ++p) { acc[a][p] = 0.f; acc2[a][p] = 0.f; }

    {
        const float* xr  = xs + pq * 8;
        const float* wr  = wT + oq * 2;
        const float* wr2 = wT + 128;
        #pragma unroll 4
        for (int c = 0; c < 64; ++c) {
            const float4 xa = *(const float4*)(xr + c * TPX);
            const float4 xb2 = *(const float4*)(xr + c * TPX + 4);
            const float2 wv = *(const float2*)(wr + c * WS2);
            const float xv[8] = {xa.x, xa.y, xa.z, xa.w, xb2.x, xb2.y, xb2.z, xb2.w};
            #pragma unroll
            for (int p = 0; p < 8; ++p) {
                acc[0][p] += wv.x * xv[p];
                acc[1][p] += wv.y * xv[p];
            }
            if (oq == 0) {
                const float2 w2 = *(const float2*)(wr2 + c * WS2);
                #pragma unroll
                for (int p = 0; p < 8; ++p) {
                    acc2[0][p] += w2.x * xv[p];
                    acc2[1][p] += w2.y * xv[p];
                }
            }
        }
    }
    __syncthreads();   // wT reads done; ys may overwrite

    // ---- Phase C: y (+bias) -> LDS ys[o][px] -----------------------------
    #pragma unroll
    for (int a = 0; a < 2; ++a) {
        const int o = 2 * oq + a;
        const float b = bs[o];
        #pragma unroll
        for (int p = 0; p < 8; ++p) ys[o * YSS + pq * 8 + p] = acc[a][p] + b;
    }
    if (oq == 0) {
        #pragma unroll
        for (int a = 0; a < 2; ++a) {
            const int o = 128 + a;
            const float b = bs[o];
            #pragma unroll
            for (int p = 0; p < 8; ++p) ys[o * YSS + pq * 8 + p] = acc2[a][p] + b;
        }
    }
    __syncthreads();

    // ---- Phase D: softmax, 8 lanes/pixel, static-indexed exp registers ---
    {
        const int spx = t >> 3;             // 0..31
        const int r   = t & 7;
        float m = -1e30f;
        #pragma unroll
        for (int i = 0; i < 9; ++i) {
            const int o = r + 8 * i;
            if (o < DB) m = fmaxf(m, ys[o * YSS + spx]);
        }
        m = fmaxf(m, __shfl_xor(m, 1));
        m = fmaxf(m, __shfl_xor(m, 2));
        m = fmaxf(m, __shfl_xor(m, 4));
        float e[9];
        float ssum = 0.f;
        #pragma unroll
        for (int i = 0; i < 9; ++i) {
            const int o = r + 8 * i;
            const float v = (o < DB) ? expf(ys[o * YSS + spx] - m) : 0.f;
            e[i] = v;
            ssum += v;
        }
        ssum += __shfl_xor(ssum, 1);
        ssum += __shfl_xor(ssum, 2);
        ssum += __shfl_xor(ssum, 4);
        const float inv = 1.f / ssum;
        #pragma unroll
        for (int i = 0; i < 9; ++i) {
            const int o = r + 8 * i;
            if (o < DB) depth_t[(size_t)(T + spx) * DB + o] = e[i] * inv;
        }
    }

    // ---- Phase E: coalesced feat stores ----------------------------------
    for (int i = t; i < TPX * CCH; i += DN_T) {
        const int px = i >> 6, o = i & 63;
        feat_t[(size_t)T * CCH + i] = ys[(DB + o) * YSS + px];
    }
}

// ---------------------------------------------------------------------------
// Kernel 2: wave = 8 points (one (ix,iy) column, g = iz) x 8 lanes.
// Lane s computes camera s's projection (no redundancy), broadcast by shfl.
// Per corner: 8-lane group loads 64 channels as 2x float4 (256B contiguous
// -> 4 cache lines vs 64 scattered). Block = 4 consecutive iy at one ix;
// final LDS transpose makes stores full 128-B lines (no cross-XCD partial
// line write amplification).
// ---------------------------------------------------------------------------
__global__ __launch_bounds__(256) void splat_kernel(
    const float* __restrict__ feat_t, const float* __restrict__ depth_t,
    const float* __restrict__ proj, float* __restrict__ out)
{
    __shared__ float trans[64 * 33];      // 8448 B, +1-pad stride
    const int t    = threadIdx.x;
    const int w    = t >> 6;              // wave in block: iy offset 0..3
    const int lane = t & 63;
    const int g    = lane >> 3;           // iz
    const int s    = lane & 7;            // sub-lane
    const int gb   = lane & 56;           // group base lane
    const int ix   = blockIdx.x >> 5;     // 0..127
    const int iy0  = 4 * (blockIdx.x & 31);
    const int iy   = iy0 + w;

    // bit-exact numpy voxel-center grid (double -> float)
    const double DXY = 102.4 / 128.0;
    const float px = (float)(-51.2 + (ix + 0.5) * DXY);
    const float py = (float)(-51.2 + (iy + 0.5) * DXY);
    const float pz = (float)(-5.0 + (g + 0.5) * 1.0);

    // ---- Stage 1: lane s projects this group's point into camera s -------
    float gxs = 0.f, gys = 0.f, gzs = -1e3f;
    bool validm = false;
    if (s < NCAM) {
        const float* M = proj + s * 16;
        const float u4 = M[0] * px + M[1] * py + M[2]  * pz + M[3];
        const float v4 = M[4] * px + M[5] * py + M[6]  * pz + M[7];
        const float z  = M[8] * px + M[9] * py + M[10] * pz + M[11];
        const float zs = fabsf(z) > 0.001f ? z : 0.001f;
        const float u = u4 / zs;
        const float v = v4 / zs;
        validm = (u >= 0.f) && (u < 1408.f) && (v >= 0.f) && (v < 512.f) &&
                 (z > 0.f) && (z < 50.f);
        if (validm) {
            gxs = u / 1408.0f * (float)FW - 0.5f;
            gys = v / 512.0f  * (float)FH - 0.5f;
            gzs = z / 50.0f   * (float)DB - 0.5f;
        }
    }
    const unsigned long long bal = __ballot(validm);
    const float cnt = (float)__popcll((bal >> (g * 8)) & 0x3Full);

    float acc[8];
    #pragma unroll
    for (int a = 0; a < 8; ++a) acc[a] = 0.f;

    // ---- Stage 2: per camera, group-uniform gather ------------------------
    for (int cam = 0; cam < NCAM; ++cam) {
        const float gx = __shfl(gxs, gb | cam);
        const float gy = __shfl(gys, gb | cam);
        const float gz = __shfl(gzs, gb | cam);
        if (gz < -500.f) continue;        // group-uniform validity

        const float xf = floorf(gx), yf = floorf(gy), zf = floorf(gz);
        const float tx = gx - xf, ty = gy - yf, tz = gz - zf;
        const int x0 = (int)xf, y0 = (int)yf, z0 = (int)zf;

        const float wz0 = (z0 >= 0 && z0 < DB) ? (1.f - tz) : 0.f;
        const float wz1 = (z0 + 1 < DB) ? tz : 0.f;
        const int zi0 = min(max(z0, 0), DB - 1);
        const int zi1 = min(max(z0 + 1, 0), DB - 1);

        float wcorn[4];
        int   pixc[4];
        #pragma unroll
        for (int dy = 0; dy < 2; ++dy) {
            const int yi = y0 + dy;
            const bool yin = (yi >= 0) & (yi < FH);
            const int yic = min(max(yi, 0), FH - 1);
            const float wy = (dy ? ty : 1.f - ty) * (yin ? 1.f : 0.f);
            #pragma unroll
            for (int dx = 0; dx < 2; ++dx) {
                const int xi = x0 + dx;
                const bool xin = (xi >= 0) & (xi < FW);
                const int xic = min(max(xi, 0), FW - 1);
                const float wx = (dx ? tx : 1.f - tx) * (xin ? 1.f : 0.f);
                wcorn[2 * dy + dx] = wx * wy;
                pixc[2 * dy + dx]  = (cam * FH + yic) * FW + xic;
            }
        }

        // depth taps: lane handles corner (s&3); duplicate lanes coalesce
        const int kc = s & 3;
        const float* dptr = depth_t + (size_t)pixc[kc] * DB;
        const float wl = wcorn[kc] * (wz0 * dptr[zi0] + wz1 * dptr[zi1]);
        const float w0 = __shfl(wl, gb | 0);
        const float w1 = __shfl(wl, gb | 1);
        const float w2 = __shfl(wl, gb | 2);
        const float w3 = __shfl(wl, gb | 3);
        const float wcs[4] = {w0, w1, w2, w3};

        // feat: per corner, 8-lane group reads 256B contiguous (2x float4)
        #pragma unroll
        for (int k = 0; k < 4; ++k) {
            const float wc = wcs[k];
            const float* fb = feat_t + (size_t)pixc[k] * CCH + s * 4;
            const float4 fa = *(const float4*)(fb);
            const float4 fh = *(const float4*)(fb + 32);
            acc[0] += wc * fa.x; acc[1] += wc * fa.y;
            acc[2] += wc * fa.z; acc[3] += wc * fa.w;
            acc[4] += wc * fh.x; acc[5] += wc * fh.y;
            acc[6] += wc * fh.z; acc[7] += wc * fh.w;
        }
    }

    // ---- Stage 3: LDS transpose -> full-line coalesced stores ------------
    const float invc = cnt > 0.f ? 1.f / cnt : 0.f;
    #pragma unroll
    for (int j = 0; j < 4; ++j) {
        trans[(4 * s + j) * 33 + w * 8 + g]      = acc[j]     * invc;
        trans[(32 + 4 * s + j) * 33 + w * 8 + g] = acc[4 + j] * invc;
    }
    __syncthreads();
    {
        const int idx = t & 31;           // covers 4 iy x 8 iz = one 128B line
        const int cb  = t >> 5;           // 0..7
        const size_t obase = (size_t)ix * (NY * NZ) + iy0 * 8 + idx;
        #pragma unroll
        for (int i = 0; i < 8; ++i) {
            const int c = cb + 8 * i;
            out[(size_t)c * NPTS + obase] = trans[c * 33 + idx];
        }
    }
}

extern "C" void kernel_launch(void* const* d_in, const int* in_sizes, int n_in,
                              void* d_out, int out_size, void* d_ws, size_t ws_size,
                              hipStream_t stream) {
    const float* x_fov = (const float*)d_in[0];   // (1,6,64,32,88)
    const float* w_dn  = (const float*)d_in[1];   // (130,64)
    const float* b_dn  = (const float*)d_in[2];   // (130,)
    const float* proj  = (const float*)d_in[4];   // (1,6,4,4)
    float* out = (float*)d_out;                   // (1,64,128,128,8)

    float* feat_t  = (float*)d_ws;                            // NPIX*64 floats
    float* depth_t = feat_t + (size_t)NPIX * CCH;             // NPIX*66 floats

    depthnet_kernel<<<NPIX / TPX, DN_T, 0, stream>>>(x_fov, w_dn, b_dn, feat_t, depth_t);

    // 4096 blocks x 4 waves; wave = one (ix,iy) column (8 iz) x 8 lanes
    splat_kernel<<<(NX * NY) / 4, 256, 0, stream>>>(feat_t, depth_t, proj, out);
}